// Round 9
// baseline (112.449 us; speedup 1.0000x reference)
//
#include <hip/hip_runtime.h>

// Bahdanau additive attention: B=8, TE=512, TD=256, H=256, fp32.
//   We = enc @ W_a; Uh = dec @ U_a
//   e[b,j,i] = softmax_i( sum_h V[h]*tanh(We[b,i,h]+Uh[b,j,h]) )
//   c[b,j,h] = sum_i e[b,j,i]*enc[b,i,h]
// d_out = [c (B*TD*H)] ++ [e (B*TD*TE)]
//
// R17 (this round): ARITHMETIC INTENSITY. R10-R16 proved phase A is not
// issue-bound (R16 packing: null) nor latency-structure-bound (R11-R14
// null). The invariant is traffic: W4 268MB + enc 268MB of L2 streaming
// per launch. This round halves the W4 stream: 8 j per block (was 4) --
// each w-load feeds 8 QSTEPs. Bonus: softmax now uses all 8 waves (was
// 4/8 idle). Phase B keeps enc read-once: 8 reg accumulators, two
// LDS-reduce rounds over the same 32KB sR. Grid 256 (8 waves/CU; R13
// showed occupancy is not the limiter). Per-element math identical ->
// absmax expected exactly 0.0004882812.
// R15 keeps: 2-kernel config, fused weight-transpose k_pre (verbatim).
// R11 keeps: 2-deep named-reg prefetch (w4, enc). R9: split-bf16 MFMA.
// R8: 4-way rcp batching. R7: XCD swizzle (b = blockIdx&7), W4 layout.

#define BB 8
#define TE 512
#define TD 256
#define HH 256

#define EXP2F(x) __builtin_amdgcn_exp2f(x)
#define RCPF(x)  __builtin_amdgcn_rcpf(x)
#define KSCALE   2.8853900817779268f    // 2*log2(e)
#define NSC      (-2.8853900817779268f) // -2*log2(e)

typedef __attribute__((ext_vector_type(8))) short short8_t;  // 8 bf16 = 4 VGPR
typedef __attribute__((ext_vector_type(4))) float f32x4;     // MFMA acc

__device__ __forceinline__ unsigned short f2bf(float x) {
    unsigned int u = __float_as_uint(x);
    return (unsigned short)((u + 0x7FFFu + ((u >> 16) & 1u)) >> 16);  // RNE
}
__device__ __forceinline__ float bf2f(unsigned short h) {
    return __uint_as_float(((unsigned int)h) << 16);
}

// ---------------------------------------------------------------------------
// k_pre (R15, verbatim): split-bf16 MFMA GEMM over X = [enc; dec], D[h][i],
// fused weight transpose. Tile 64h x 64i, 384 blocks, K-chunks of 32.
// Fragment layouts (m89-verified):
//   A/B frags: row/col = l&15, k-octet = (l>>4)*8; D: col=l&15, row=(l>>4)*4+reg.
// ---------------------------------------------------------------------------
__global__ __launch_bounds__(256) void k_pre(
    const float* __restrict__ enc, const float* __restrict__ dec,
    const float* __restrict__ Wa,  const float* __restrict__ Ua,
    float* __restrict__ W4, float* __restrict__ Uhe)
{
    const int t  = threadIdx.x;
    const int it = blockIdx.x >> 2;       // 0..95  (i-tile)
    const int ht = blockIdx.x & 3;        // 0..3   (h-tile)
    const int i0 = it * 64;
    const int h0 = ht * 64;
    const bool is_enc = (i0 < BB * TE);   // < 4096
    const float* X  = is_enc ? (enc + (size_t)i0 * HH)
                             : (dec + (size_t)(i0 - BB * TE) * HH);
    const float* Wg = is_enc ? Wa : Ua;

    __shared__ unsigned short At_h[64][40], At_l[64][40];
    __shared__ unsigned short Xs_h[64][40], Xs_l[64][40];
    __shared__ float T[32][66];           // fp32 W chunk, padded

    const int sr = t >> 2;                // X staging row / At pass-2 h (0..63)
    const int sq = (t & 3) * 8;           // k-octet (0,8,16,24)
    const int kr = t >> 3;                // W load k-row (0..31)
    const int hc = (t & 7) * 8;           // W load h-base (0..56)

    const int wv = t >> 6, l = t & 63;
    const int wh = (wv & 1) * 32;
    const int wi = (wv >> 1) * 32;
    const int fr = l & 15;
    const int fk = (l >> 4) * 8;
    const int rq = l >> 4;                // D row-quad

    f32x4 acc[2][2];
    #pragma unroll
    for (int a0 = 0; a0 < 2; a0++)
        #pragma unroll
        for (int a1 = 0; a1 < 2; a1++)
            acc[a0][a1] = (f32x4){0.f, 0.f, 0.f, 0.f};

    float4 x0  = *(const float4*)(X + (size_t)sr * HH + sq);
    float4 x1  = *(const float4*)(X + (size_t)sr * HH + sq + 4);
    float4 wf0 = *(const float4*)(Wg + (size_t)kr * HH + h0 + hc);
    float4 wf1 = *(const float4*)(Wg + (size_t)kr * HH + h0 + hc + 4);

    #pragma unroll
    for (int c = 0; c < 8; c++) {
        short8_t xh, xl;
        {
            unsigned short h;
            h = f2bf(x0.x); xh[0] = (short)h; xl[0] = (short)f2bf(x0.x - bf2f(h));
            h = f2bf(x0.y); xh[1] = (short)h; xl[1] = (short)f2bf(x0.y - bf2f(h));
            h = f2bf(x0.z); xh[2] = (short)h; xl[2] = (short)f2bf(x0.z - bf2f(h));
            h = f2bf(x0.w); xh[3] = (short)h; xl[3] = (short)f2bf(x0.w - bf2f(h));
            h = f2bf(x1.x); xh[4] = (short)h; xl[4] = (short)f2bf(x1.x - bf2f(h));
            h = f2bf(x1.y); xh[5] = (short)h; xl[5] = (short)f2bf(x1.y - bf2f(h));
            h = f2bf(x1.z); xh[6] = (short)h; xl[6] = (short)f2bf(x1.z - bf2f(h));
            h = f2bf(x1.w); xh[7] = (short)h; xl[7] = (short)f2bf(x1.w - bf2f(h));
        }
        __syncthreads();   // B1: prior chunk's MFMA readers done
        *(short8_t*)&Xs_h[sr][sq] = xh;
        *(short8_t*)&Xs_l[sr][sq] = xl;
        {
            float2 a, b;
            a.x = wf0.x; a.y = wf0.y; b.x = wf0.z; b.y = wf0.w;
            *(float2*)&T[kr][hc]     = a;
            *(float2*)&T[kr][hc + 2] = b;
            a.x = wf1.x; a.y = wf1.y; b.x = wf1.z; b.y = wf1.w;
            *(float2*)&T[kr][hc + 4] = a;
            *(float2*)&T[kr][hc + 6] = b;
        }
        __syncthreads();   // B2: T + Xs ready
        {
            short8_t ah_, al_;
            #pragma unroll
            for (int e = 0; e < 8; e++) {
                float f = T[sq + e][sr];
                unsigned short h = f2bf(f);
                ah_[e] = (short)h;
                al_[e] = (short)f2bf(f - bf2f(h));
            }
            *(short8_t*)&At_h[sr][sq] = ah_;
            *(short8_t*)&At_l[sr][sq] = al_;
        }
        if (c < 7) {
            const int kc = (c + 1) * 32;
            x0  = *(const float4*)(X + (size_t)sr * HH + kc + sq);
            x1  = *(const float4*)(X + (size_t)sr * HH + kc + sq + 4);
            wf0 = *(const float4*)(Wg + (size_t)(kc + kr) * HH + h0 + hc);
            wf1 = *(const float4*)(Wg + (size_t)(kc + kr) * HH + h0 + hc + 4);
        }
        __syncthreads();   // B3: At ready
        #pragma unroll
        for (int fm = 0; fm < 2; fm++) {
            short8_t a_h = *(const short8_t*)&At_h[wh + 16 * fm + fr][fk];
            short8_t a_l = *(const short8_t*)&At_l[wh + 16 * fm + fr][fk];
            #pragma unroll
            for (int fn = 0; fn < 2; fn++) {
                short8_t b_h = *(const short8_t*)&Xs_h[wi + 16 * fn + fr][fk];
                short8_t b_l = *(const short8_t*)&Xs_l[wi + 16 * fn + fr][fk];
                acc[fm][fn] = __builtin_amdgcn_mfma_f32_16x16x32_bf16(a_h, b_h, acc[fm][fn], 0, 0, 0);
                acc[fm][fn] = __builtin_amdgcn_mfma_f32_16x16x32_bf16(a_h, b_l, acc[fm][fn], 0, 0, 0);
                acc[fm][fn] = __builtin_amdgcn_mfma_f32_16x16x32_bf16(a_l, b_h, acc[fm][fn], 0, 0, 0);
            }
        }
    }

    #pragma unroll
    for (int fm = 0; fm < 2; fm++) {
        #pragma unroll
        for (int fn = 0; fn < 2; fn++) {
            f32x4 v = acc[fm][fn];
            float4 o;
            o.x = EXP2F(v[0] * KSCALE);
            o.y = EXP2F(v[1] * KSCALE);
            o.z = EXP2F(v[2] * KSCALE);
            o.w = EXP2F(v[3] * KSCALE);
            const int ig = i0 + wi + 16 * fn + fr;      // global concat row
            const int hb = h0 + wh + 16 * fm + rq * 4;  // 4 consecutive h
            if (is_enc) {
                const int b  = ig >> 9;                 // 512 enc rows per batch
                const int ib = ig & 511;
                const int hq = hb >> 2;
                *(float4*)(W4 + (((size_t)b * 64 + hq) * TE + ib) * 4) = o;
            } else {
                const int j = ig - BB * TE;             // global dec row
                *(float4*)(Uhe + (size_t)j * HH + hb) = o;
            }
        }
    }
}

// ---------------------------------------------------------------------------
// k_attn (R17): 512 threads = 8 waves; block owns EIGHT consecutive j's of
// ONE batch, batch = blockIdx&7 (XCD-local). Grid 256 (32 j-groups/batch).
// Phase A: lane owns i = 64*wv+lane; each w4 load feeds 8 QSTEPs (W4
// traffic halved vs 4-j). 2-deep named-reg prefetch of the w4 stream.
// Softmax: ALL 8 waves (wave w -> j0+w). Phase B: 8 reg accumulators
// (enc read once), then two LDS-reduce rounds over the same 32KB sR.
// ---------------------------------------------------------------------------
__global__ __launch_bounds__(512) void k_attn(
    const float* __restrict__ enc, const float* __restrict__ W4,
    const float* __restrict__ Uhe, const float* __restrict__ Va,
    float* __restrict__ out_c, float* __restrict__ out_e)
{
    const int wv = threadIdx.x >> 6, lane = threadIdx.x & 63;
    const int b   = blockIdx.x & 7;           // XCD-local batch
    const int j0  = (blockIdx.x >> 3) * 8;    // 32 j-groups per batch
    const int jj0 = b * TD + j0;              // block-uniform

    __shared__ float sP[8][TE];      // 16 KB: energies -> probabilities
    __shared__ float sR[8][4][HH];   // 32 KB: phase-B reduce (2 rounds)

    const int i = (wv << 6) + lane;
    const float* wp = W4 + ((size_t)b * 64 * TE + i) * 4;
    const float* ua = Uhe + (size_t)jj0 * HH;   // block-uniform -> s_load
    const float* va = Va;                        // uniform

    float a0 = 0.f, a1 = 0.f, a2 = 0.f, a3 = 0.f;
    float a4 = 0.f, a5 = 0.f, a6 = 0.f, a7 = 0.f;

    // 4-way batched reciprocal:
    //   sum_k v_k/A_k = (nAB*dCD + nCD*dAB) / (dAB*dCD)
#define QSTEP(ACC, U)                                                     \
    {                                                                     \
        float A_ = fmaf(w4.x, (U).x, 1.f);                                \
        float B_ = fmaf(w4.y, (U).y, 1.f);                                \
        float C_ = fmaf(w4.z, (U).z, 1.f);                                \
        float D_ = fmaf(w4.w, (U).w, 1.f);                                \
        float dAB = A_ * B_, dCD = C_ * D_;                               \
        float nAB = fmaf(v4.x, B_, v4.y * A_);                            \
        float nCD = fmaf(v4.z, D_, v4.w * C_);                            \
        float num = fmaf(nAB, dCD, nCD * dAB);                            \
        ACC = fmaf(num, RCPF(dAB * dCD), ACC);                            \
    }

#define ASTEP(Q, W4V)                                                     \
    {                                                                     \
        float4 w4 = W4V;                                                  \
        float4 v4 = *(const float4*)(va + 4 * (Q));                       \
        float4 u0 = *(const float4*)(ua + 4 * (Q));                       \
        float4 u1 = *(const float4*)(ua + HH + 4 * (Q));                  \
        float4 u2 = *(const float4*)(ua + 2 * HH + 4 * (Q));              \
        float4 u3 = *(const float4*)(ua + 3 * HH + 4 * (Q));              \
        float4 u4 = *(const float4*)(ua + 4 * HH + 4 * (Q));              \
        float4 u5 = *(const float4*)(ua + 5 * HH + 4 * (Q));              \
        float4 u6 = *(const float4*)(ua + 6 * HH + 4 * (Q));              \
        float4 u7 = *(const float4*)(ua + 7 * HH + 4 * (Q));              \
        QSTEP(a0, u0)                                                     \
        QSTEP(a1, u1)                                                     \
        QSTEP(a2, u2)                                                     \
        QSTEP(a3, u3)                                                     \
        QSTEP(a4, u4)                                                     \
        QSTEP(a5, u5)                                                     \
        QSTEP(a6, u6)                                                     \
        QSTEP(a7, u7)                                                     \
    }

    // 2-deep software pipeline on the per-lane w4 stream
    float4 wA = *(const float4*)(wp);
    float4 wB = *(const float4*)(wp + (size_t)TE * 4);
    for (int q = 0; q < 64; q += 2) {
        float4 wC = *(const float4*)(wp + (size_t)(q + 2) * TE * 4);
        float4 wD = *(const float4*)(wp + (size_t)(q + 3) * TE * 4);
        ASTEP(q, wA)
        ASTEP(q + 1, wB)
        wA = wC; wB = wD;
    }
#undef ASTEP
#undef QSTEP

    // conflict-free b32 writes (lane-stride 4B), energies in log2 domain
    sP[0][i] = NSC * a0;
    sP[1][i] = NSC * a1;
    sP[2][i] = NSC * a2;
    sP[3][i] = NSC * a3;
    sP[4][i] = NSC * a4;
    sP[5][i] = NSC * a5;
    sP[6][i] = NSC * a6;
    sP[7][i] = NSC * a7;
    __syncthreads();

    // ---- softmax: ALL 8 waves; wave w handles j0+w -----------------------
    {
        float ev[8];
        float m = -3.0e38f;
        #pragma unroll
        for (int k = 0; k < 8; k++) {
            ev[k] = sP[wv][lane + 64 * k];
            m = fmaxf(m, ev[k]);
        }
        #pragma unroll
        for (int off = 32; off; off >>= 1) m = fmaxf(m, __shfl_xor(m, off, 64));
        float s = 0.f;
        #pragma unroll
        for (int k = 0; k < 8; k++) { ev[k] = EXP2F(ev[k] - m); s += ev[k]; }
        #pragma unroll
        for (int off = 32; off; off >>= 1) s += __shfl_xor(s, off, 64);
        float rs = RCPF(s);
        float* oe = out_e + (size_t)(jj0 + wv) * TE;
        #pragma unroll
        for (int k = 0; k < 8; k++) {
            float p = ev[k] * rs;
            sP[wv][lane + 64 * k] = p;
            oe[lane + 64 * k] = p;
        }
    }
    __syncthreads();

    // ---- Phase B: wave w -> i in [64w, 64w+64), all 8 j (enc read once) --
    const int ib = wv << 6;
    const float* eb = enc + ((size_t)b * TE + ib) * HH + 4 * lane;
    float4 c0 = {0,0,0,0}, c1 = {0,0,0,0}, c2 = {0,0,0,0}, c3 = {0,0,0,0};
    float4 c4 = {0,0,0,0}, c5 = {0,0,0,0}, c6 = {0,0,0,0}, c7 = {0,0,0,0};

#define BSTEP(K, QV)                                                      \
    {                                                                     \
        float p0 = sP[0][ib + (K)];                                       \
        float p1 = sP[1][ib + (K)];                                       \
        float p2 = sP[2][ib + (K)];                                       \
        float p3 = sP[3][ib + (K)];                                       \
        float p4 = sP[4][ib + (K)];                                       \
        float p5 = sP[5][ib + (K)];                                       \
        float p6 = sP[6][ib + (K)];                                       \
        float p7 = sP[7][ib + (K)];                                       \
        float4 q = QV;                                                    \
        c0.x = fmaf(p0, q.x, c0.x); c0.y = fmaf(p0, q.y, c0.y);           \
        c0.z = fmaf(p0, q.z, c0.z); c0.w = fmaf(p0, q.w, c0.w);           \
        c1.x = fmaf(p1, q.x, c1.x); c1.y = fmaf(p1, q.y, c1.y);           \
        c1.z = fmaf(p1, q.z, c1.z); c1.w = fmaf(p1, q.w, c1.w);           \
        c2.x = fmaf(p2, q.x, c2.x); c2.y = fmaf(p2, q.y, c2.y);           \
        c2.z = fmaf(p2, q.z, c2.z); c2.w = fmaf(p2, q.w, c2.w);           \
        c3.x = fmaf(p3, q.x, c3.x); c3.y = fmaf(p3, q.y, c3.y);           \
        c3.z = fmaf(p3, q.z, c3.z); c3.w = fmaf(p3, q.w, c3.w);           \
        c4.x = fmaf(p4, q.x, c4.x); c4.y = fmaf(p4, q.y, c4.y);           \
        c4.z = fmaf(p4, q.z, c4.z); c4.w = fmaf(p4, q.w, c4.w);           \
        c5.x = fmaf(p5, q.x, c5.x); c5.y = fmaf(p5, q.y, c5.y);           \
        c5.z = fmaf(p5, q.z, c5.z); c5.w = fmaf(p5, q.w, c5.w);           \
        c6.x = fmaf(p6, q.x, c6.x); c6.y = fmaf(p6, q.y, c6.y);           \
        c6.z = fmaf(p6, q.z, c6.z); c6.w = fmaf(p6, q.w, c6.w);           \
        c7.x = fmaf(p7, q.x, c7.x); c7.y = fmaf(p7, q.y, c7.y);           \
        c7.z = fmaf(p7, q.z, c7.z); c7.w = fmaf(p7, q.w, c7.w);           \
    }

    // 2-deep software pipeline on the per-lane enc stream (tail clamped)
    float4 qA = *(const float4*)(eb);
    float4 qB = *(const float4*)(eb + (size_t)HH);
    for (int k = 0; k < 64; k += 2) {
        const int k2 = (k + 2 < 64) ? k + 2 : 62;
        const int k3 = (k + 3 < 64) ? k + 3 : 63;
        float4 qC = *(const float4*)(eb + (size_t)k2 * HH);
        float4 qD = *(const float4*)(eb + (size_t)k3 * HH);
        BSTEP(k, qA)
        BSTEP(k + 1, qB)
        qA = qC; qB = qD;
    }
#undef BSTEP

    // ---- reduce round 1: j0..j3 ------------------------------------------
    *(float4*)&sR[wv][0][4 * lane] = c0;
    *(float4*)&sR[wv][1][4 * lane] = c1;
    *(float4*)&sR[wv][2][4 * lane] = c2;
    *(float4*)&sR[wv][3][4 * lane] = c3;
    __syncthreads();
    {
        const int jr = wv & 3;
        const int h2 = (wv >> 2) * 128 + 2 * lane;
        float sx = 0.f, sy = 0.f;
        #pragma unroll
        for (int ww = 0; ww < 8; ww++) {
            float2 tv = *(const float2*)&sR[ww][jr][h2];
            sx += tv.x; sy += tv.y;
        }
        float2 o; o.x = sx; o.y = sy;
        *(float2*)(out_c + (size_t)(jj0 + jr) * HH + h2) = o;
    }
    __syncthreads();

    // ---- reduce round 2: j4..j7 ------------------------------------------
    *(float4*)&sR[wv][0][4 * lane] = c4;
    *(float4*)&sR[wv][1][4 * lane] = c5;
    *(float4*)&sR[wv][2][4 * lane] = c6;
    *(float4*)&sR[wv][3][4 * lane] = c7;
    __syncthreads();
    {
        const int jr = wv & 3;
        const int h2 = (wv >> 2) * 128 + 2 * lane;
        float sx = 0.f, sy = 0.f;
        #pragma unroll
        for (int ww = 0; ww < 8; ww++) {
            float2 tv = *(const float2*)&sR[ww][jr][h2];
            sx += tv.x; sy += tv.y;
        }
        float2 o; o.x = sx; o.y = sy;
        *(float2*)(out_c + (size_t)(jj0 + 4 + jr) * HH + h2) = o;
    }
}

extern "C" void kernel_launch(void* const* d_in, const int* in_sizes, int n_in,
                              void* d_out, int out_size, void* d_ws, size_t ws_size,
                              hipStream_t stream) {
    const float* enc = (const float*)d_in[0];
    const float* dec = (const float*)d_in[1];
    const float* Wa  = (const float*)d_in[2];
    const float* Ua  = (const float*)d_in[3];
    const float* Va  = (const float*)d_in[4];

    float* W4  = (float*)d_ws;                        // exp2-domain, interleaved (4MB)
    float* Uhe = W4 + (size_t)BB * HH * TE;           // exp2-domain, B*TD*H (2MB)

    float* out_c = (float*)d_out;                     // [B,TD,H]
    float* out_e = out_c + (size_t)BB * TD * HH;      // [B,TD,TE]

    k_pre<<<384, 256, 0, stream>>>(enc, dec, Wa, Ua, W4, Uhe);
    k_attn<<<BB * TD / 8, 512, 0, stream>>>(enc, W4, Uhe, Va, out_c, out_e);
}

// Round 10
// 108.121 us; speedup vs baseline: 1.0400x; 1.0400x over previous
//
#include <hip/hip_runtime.h>

// Bahdanau additive attention: B=8, TE=512, TD=256, H=256, fp32.
//   We = enc @ W_a; Uh = dec @ U_a
//   e[b,j,i] = softmax_i( sum_h V[h]*tanh(We[b,i,h]+Uh[b,j,h]) )
//   c[b,j,h] = sum_i e[b,j,i]*enc[b,i,h]
// d_out = [c (B*TD*H)] ++ [e (B*TD*TE)]
//
// R18 (this round): SCALAR-PIPE WIDTH. Unifying theory for R10-R17 nulls:
// phase A saturates the scalar-memory pipe (5 s_load_dwordx4 per q-step,
// ~1.3M s_loads, ~17us of unhideable serialization -- occupancy-proof,
// VALU-count-proof, traffic-proof, j-count-proof: u-loads scale WITH j).
// Fix: 4x wider scalar loads. Phase A = 16 super-iters x 4 quads; per
// super-iter: 4 uniform s_load_dwordx16 (u rows) + 1 x16 (v) = 5 SMEM
// instrs per 4096 elements (was 20). Element math and accumulation order
// byte-identical -> absmax must stay exactly 0.0004882812.
// R15 keeps: 2-kernel config, fused weight-transpose k_pre (verbatim).
// R11 keeps: named-reg prefetch (w4, enc). R9: split-bf16 MFMA.
// R8: 4-way rcp batching. R7: XCD swizzle (b = blockIdx&7), W4 layout.

#define BB 8
#define TE 512
#define TD 256
#define HH 256

#define EXP2F(x) __builtin_amdgcn_exp2f(x)
#define RCPF(x)  __builtin_amdgcn_rcpf(x)
#define KSCALE   2.8853900817779268f    // 2*log2(e)
#define NSC      (-2.8853900817779268f) // -2*log2(e)

typedef __attribute__((ext_vector_type(8))) short short8_t;  // 8 bf16 = 4 VGPR
typedef __attribute__((ext_vector_type(4))) float f32x4;     // MFMA acc
typedef __attribute__((ext_vector_type(16))) float f32x16;   // s_load_dwordx16

__device__ __forceinline__ unsigned short f2bf(float x) {
    unsigned int u = __float_as_uint(x);
    return (unsigned short)((u + 0x7FFFu + ((u >> 16) & 1u)) >> 16);  // RNE
}
__device__ __forceinline__ float bf2f(unsigned short h) {
    return __uint_as_float(((unsigned int)h) << 16);
}

// ---------------------------------------------------------------------------
// k_pre (R15, verbatim): split-bf16 MFMA GEMM over X = [enc; dec], D[h][i],
// fused weight transpose. Tile 64h x 64i, 384 blocks, K-chunks of 32.
// Fragment layouts (m89-verified):
//   A/B frags: row/col = l&15, k-octet = (l>>4)*8; D: col=l&15, row=(l>>4)*4+reg.
// ---------------------------------------------------------------------------
__global__ __launch_bounds__(256) void k_pre(
    const float* __restrict__ enc, const float* __restrict__ dec,
    const float* __restrict__ Wa,  const float* __restrict__ Ua,
    float* __restrict__ W4, float* __restrict__ Uhe)
{
    const int t  = threadIdx.x;
    const int it = blockIdx.x >> 2;       // 0..95  (i-tile)
    const int ht = blockIdx.x & 3;        // 0..3   (h-tile)
    const int i0 = it * 64;
    const int h0 = ht * 64;
    const bool is_enc = (i0 < BB * TE);   // < 4096
    const float* X  = is_enc ? (enc + (size_t)i0 * HH)
                             : (dec + (size_t)(i0 - BB * TE) * HH);
    const float* Wg = is_enc ? Wa : Ua;

    __shared__ unsigned short At_h[64][40], At_l[64][40];
    __shared__ unsigned short Xs_h[64][40], Xs_l[64][40];
    __shared__ float T[32][66];           // fp32 W chunk, padded

    const int sr = t >> 2;                // X staging row / At pass-2 h (0..63)
    const int sq = (t & 3) * 8;           // k-octet (0,8,16,24)
    const int kr = t >> 3;                // W load k-row (0..31)
    const int hc = (t & 7) * 8;           // W load h-base (0..56)

    const int wv = t >> 6, l = t & 63;
    const int wh = (wv & 1) * 32;
    const int wi = (wv >> 1) * 32;
    const int fr = l & 15;
    const int fk = (l >> 4) * 8;
    const int rq = l >> 4;                // D row-quad

    f32x4 acc[2][2];
    #pragma unroll
    for (int a0 = 0; a0 < 2; a0++)
        #pragma unroll
        for (int a1 = 0; a1 < 2; a1++)
            acc[a0][a1] = (f32x4){0.f, 0.f, 0.f, 0.f};

    float4 x0  = *(const float4*)(X + (size_t)sr * HH + sq);
    float4 x1  = *(const float4*)(X + (size_t)sr * HH + sq + 4);
    float4 wf0 = *(const float4*)(Wg + (size_t)kr * HH + h0 + hc);
    float4 wf1 = *(const float4*)(Wg + (size_t)kr * HH + h0 + hc + 4);

    #pragma unroll
    for (int c = 0; c < 8; c++) {
        short8_t xh, xl;
        {
            unsigned short h;
            h = f2bf(x0.x); xh[0] = (short)h; xl[0] = (short)f2bf(x0.x - bf2f(h));
            h = f2bf(x0.y); xh[1] = (short)h; xl[1] = (short)f2bf(x0.y - bf2f(h));
            h = f2bf(x0.z); xh[2] = (short)h; xl[2] = (short)f2bf(x0.z - bf2f(h));
            h = f2bf(x0.w); xh[3] = (short)h; xl[3] = (short)f2bf(x0.w - bf2f(h));
            h = f2bf(x1.x); xh[4] = (short)h; xl[4] = (short)f2bf(x1.x - bf2f(h));
            h = f2bf(x1.y); xh[5] = (short)h; xl[5] = (short)f2bf(x1.y - bf2f(h));
            h = f2bf(x1.z); xh[6] = (short)h; xl[6] = (short)f2bf(x1.z - bf2f(h));
            h = f2bf(x1.w); xh[7] = (short)h; xl[7] = (short)f2bf(x1.w - bf2f(h));
        }
        __syncthreads();   // B1: prior chunk's MFMA readers done
        *(short8_t*)&Xs_h[sr][sq] = xh;
        *(short8_t*)&Xs_l[sr][sq] = xl;
        {
            float2 a, b;
            a.x = wf0.x; a.y = wf0.y; b.x = wf0.z; b.y = wf0.w;
            *(float2*)&T[kr][hc]     = a;
            *(float2*)&T[kr][hc + 2] = b;
            a.x = wf1.x; a.y = wf1.y; b.x = wf1.z; b.y = wf1.w;
            *(float2*)&T[kr][hc + 4] = a;
            *(float2*)&T[kr][hc + 6] = b;
        }
        __syncthreads();   // B2: T + Xs ready
        {
            short8_t ah_, al_;
            #pragma unroll
            for (int e = 0; e < 8; e++) {
                float f = T[sq + e][sr];
                unsigned short h = f2bf(f);
                ah_[e] = (short)h;
                al_[e] = (short)f2bf(f - bf2f(h));
            }
            *(short8_t*)&At_h[sr][sq] = ah_;
            *(short8_t*)&At_l[sr][sq] = al_;
        }
        if (c < 7) {
            const int kc = (c + 1) * 32;
            x0  = *(const float4*)(X + (size_t)sr * HH + kc + sq);
            x1  = *(const float4*)(X + (size_t)sr * HH + kc + sq + 4);
            wf0 = *(const float4*)(Wg + (size_t)(kc + kr) * HH + h0 + hc);
            wf1 = *(const float4*)(Wg + (size_t)(kc + kr) * HH + h0 + hc + 4);
        }
        __syncthreads();   // B3: At ready
        #pragma unroll
        for (int fm = 0; fm < 2; fm++) {
            short8_t a_h = *(const short8_t*)&At_h[wh + 16 * fm + fr][fk];
            short8_t a_l = *(const short8_t*)&At_l[wh + 16 * fm + fr][fk];
            #pragma unroll
            for (int fn = 0; fn < 2; fn++) {
                short8_t b_h = *(const short8_t*)&Xs_h[wi + 16 * fn + fr][fk];
                short8_t b_l = *(const short8_t*)&Xs_l[wi + 16 * fn + fr][fk];
                acc[fm][fn] = __builtin_amdgcn_mfma_f32_16x16x32_bf16(a_h, b_h, acc[fm][fn], 0, 0, 0);
                acc[fm][fn] = __builtin_amdgcn_mfma_f32_16x16x32_bf16(a_h, b_l, acc[fm][fn], 0, 0, 0);
                acc[fm][fn] = __builtin_amdgcn_mfma_f32_16x16x32_bf16(a_l, b_h, acc[fm][fn], 0, 0, 0);
            }
        }
    }

    #pragma unroll
    for (int fm = 0; fm < 2; fm++) {
        #pragma unroll
        for (int fn = 0; fn < 2; fn++) {
            f32x4 v = acc[fm][fn];
            float4 o;
            o.x = EXP2F(v[0] * KSCALE);
            o.y = EXP2F(v[1] * KSCALE);
            o.z = EXP2F(v[2] * KSCALE);
            o.w = EXP2F(v[3] * KSCALE);
            const int ig = i0 + wi + 16 * fn + fr;      // global concat row
            const int hb = h0 + wh + 16 * fm + rq * 4;  // 4 consecutive h
            if (is_enc) {
                const int b  = ig >> 9;                 // 512 enc rows per batch
                const int ib = ig & 511;
                const int hq = hb >> 2;
                *(float4*)(W4 + (((size_t)b * 64 + hq) * TE + ib) * 4) = o;
            } else {
                const int j = ig - BB * TE;             // global dec row
                *(float4*)(Uhe + (size_t)j * HH + hb) = o;
            }
        }
    }
}

// ---------------------------------------------------------------------------
// k_attn (R18): 512 threads = 8 waves; block owns 4 consecutive j's of ONE
// batch, batch = blockIdx&7 (XCD-local).
// Phase A: 16 super-iters x 4 quads. Per super-iter: 4 per-lane dwordx4
// w-loads (1-deep prefetch) + 4 uniform s_load_dwordx16 (u rows) + 1 x16
// (v) -- 4x fewer scalar-pipe slots than the per-quad dwordx4 form.
// Softmax: waves 0-3. Phase B: 2-deep prefetch on enc (unchanged).
// ---------------------------------------------------------------------------
__global__ __launch_bounds__(512) void k_attn(
    const float* __restrict__ enc, const float* __restrict__ W4,
    const float* __restrict__ Uhe, const float* __restrict__ Va,
    float* __restrict__ out_c, float* __restrict__ out_e)
{
    const int wv = threadIdx.x >> 6, lane = threadIdx.x & 63;
    const int b   = blockIdx.x & 7;           // XCD-local batch
    const int j0  = (blockIdx.x >> 3) * 4;    // 64 j-groups per batch
    const int jj0 = b * TD + j0;              // block-uniform

    __shared__ float sP[4][TE];      // 8 KB: energies -> probabilities
    __shared__ float sR[8][4][HH];   // 32 KB: phase-B partials

    const int i = (wv << 6) + lane;
    const float* wp = W4 + ((size_t)b * 64 * TE + i) * 4;
    const float* ua = Uhe + (size_t)jj0 * HH;   // block-uniform, 64B-aligned
    const float* va = Va;                        // uniform, 64B-aligned

    float a0 = 0.f, a1 = 0.f, a2 = 0.f, a3 = 0.f;

    // 4-way batched reciprocal (quad RR of the super-iter):
    //   sum_k v_k/A_k = (nAB*dCD + nCD*dAB) / (dAB*dCD)
#define QSTEP(ACC, UX, RR)                                                \
    {                                                                     \
        float A_ = fmaf(w4.x, (UX)[4*(RR)+0], 1.f);                       \
        float B_ = fmaf(w4.y, (UX)[4*(RR)+1], 1.f);                       \
        float C_ = fmaf(w4.z, (UX)[4*(RR)+2], 1.f);                       \
        float D_ = fmaf(w4.w, (UX)[4*(RR)+3], 1.f);                       \
        float dAB = A_ * B_, dCD = C_ * D_;                               \
        float nAB = fmaf(vx[4*(RR)+0], B_, vx[4*(RR)+1] * A_);            \
        float nCD = fmaf(vx[4*(RR)+2], D_, vx[4*(RR)+3] * C_);            \
        float num = fmaf(nAB, dCD, nCD * dAB);                            \
        ACC = fmaf(num, RCPF(dAB * dCD), ACC);                            \
    }

#define RSTEP(RR, WV)                                                    \
    {                                                                     \
        float4 w4 = WV;                                                   \
        QSTEP(a0, u0x, RR)                                                \
        QSTEP(a1, u1x, RR)                                                \
        QSTEP(a2, u2x, RR)                                                \
        QSTEP(a3, u3x, RR)                                                \
    }

    // 1-deep prefetch of the per-lane w quads; uniform u/v as x16 rows
    float4 wA0 = *(const float4*)(wp + 0 * (size_t)TE * 4);
    float4 wA1 = *(const float4*)(wp + 1 * (size_t)TE * 4);
    float4 wA2 = *(const float4*)(wp + 2 * (size_t)TE * 4);
    float4 wA3 = *(const float4*)(wp + 3 * (size_t)TE * 4);
    for (int s = 0; s < 16; s++) {
        const int nq = (s < 15) ? 4 * (s + 1) : 60;   // tail re-read (safe)
        float4 wB0 = *(const float4*)(wp + (size_t)(nq + 0) * TE * 4);
        float4 wB1 = *(const float4*)(wp + (size_t)(nq + 1) * TE * 4);
        float4 wB2 = *(const float4*)(wp + (size_t)(nq + 2) * TE * 4);
        float4 wB3 = *(const float4*)(wp + (size_t)(nq + 3) * TE * 4);
        f32x16 vx  = *(const f32x16*)(va + 16 * s);
        f32x16 u0x = *(const f32x16*)(ua + 16 * s);
        f32x16 u1x = *(const f32x16*)(ua + HH + 16 * s);
        f32x16 u2x = *(const f32x16*)(ua + 2 * HH + 16 * s);
        f32x16 u3x = *(const f32x16*)(ua + 3 * HH + 16 * s);
        RSTEP(0, wA0)
        RSTEP(1, wA1)
        RSTEP(2, wA2)
        RSTEP(3, wA3)
        wA0 = wB0; wA1 = wB1; wA2 = wB2; wA3 = wB3;
    }
#undef RSTEP
#undef QSTEP

    // conflict-free b32 writes (lane-stride 4B), energies in log2 domain
    sP[0][i] = NSC * a0;
    sP[1][i] = NSC * a1;
    sP[2][i] = NSC * a2;
    sP[3][i] = NSC * a3;
    __syncthreads();

    // ---- softmax: wave w in 0..3 handles j0+w ----------------------------
    if (wv < 4) {
        float ev[8];
        float m = -3.0e38f;
        #pragma unroll
        for (int k = 0; k < 8; k++) {
            ev[k] = sP[wv][lane + 64 * k];
            m = fmaxf(m, ev[k]);
        }
        #pragma unroll
        for (int off = 32; off; off >>= 1) m = fmaxf(m, __shfl_xor(m, off, 64));
        float s = 0.f;
        #pragma unroll
        for (int k = 0; k < 8; k++) { ev[k] = EXP2F(ev[k] - m); s += ev[k]; }
        #pragma unroll
        for (int off = 32; off; off >>= 1) s += __shfl_xor(s, off, 64);
        float rs = RCPF(s);
        float* oe = out_e + (size_t)(jj0 + wv) * TE;
        #pragma unroll
        for (int k = 0; k < 8; k++) {
            float p = ev[k] * rs;
            sP[wv][lane + 64 * k] = p;
            oe[lane + 64 * k] = p;
        }
    }
    __syncthreads();

    // ---- Phase B: wave w -> i in [64w, 64w+64), all 4 j ------------------
    const int ib = wv << 6;
    const float* eb = enc + ((size_t)b * TE + ib) * HH + 4 * lane;
    float4 c0 = {0,0,0,0}, c1 = {0,0,0,0}, c2 = {0,0,0,0}, c3 = {0,0,0,0};

#define BSTEP(K, QV)                                                      \
    {                                                                     \
        float p0 = sP[0][ib + (K)];                                       \
        float p1 = sP[1][ib + (K)];                                       \
        float p2 = sP[2][ib + (K)];                                       \
        float p3 = sP[3][ib + (K)];                                       \
        float4 q = QV;                                                    \
        c0.x = fmaf(p0, q.x, c0.x); c0.y = fmaf(p0, q.y, c0.y);           \
        c0.z = fmaf(p0, q.z, c0.z); c0.w = fmaf(p0, q.w, c0.w);           \
        c1.x = fmaf(p1, q.x, c1.x); c1.y = fmaf(p1, q.y, c1.y);           \
        c1.z = fmaf(p1, q.z, c1.z); c1.w = fmaf(p1, q.w, c1.w);           \
        c2.x = fmaf(p2, q.x, c2.x); c2.y = fmaf(p2, q.y, c2.y);           \
        c2.z = fmaf(p2, q.z, c2.z); c2.w = fmaf(p2, q.w, c2.w);           \
        c3.x = fmaf(p3, q.x, c3.x); c3.y = fmaf(p3, q.y, c3.y);           \
        c3.z = fmaf(p3, q.z, c3.z); c3.w = fmaf(p3, q.w, c3.w);           \
    }

    // 2-deep software pipeline on the per-lane enc stream (tail clamped:
    // enc is an input buffer, no OOB reads allowed)
    float4 qA = *(const float4*)(eb);
    float4 qB = *(const float4*)(eb + (size_t)HH);
    for (int k = 0; k < 64; k += 2) {
        const int k2 = (k + 2 < 64) ? k + 2 : 62;
        const int k3 = (k + 3 < 64) ? k + 3 : 63;
        float4 qC = *(const float4*)(eb + (size_t)k2 * HH);
        float4 qD = *(const float4*)(eb + (size_t)k3 * HH);
        BSTEP(k, qA)
        BSTEP(k + 1, qB)
        qA = qC; qB = qD;
    }
#undef BSTEP

    *(float4*)&sR[wv][0][4 * lane] = c0;
    *(float4*)&sR[wv][1][4 * lane] = c1;
    *(float4*)&sR[wv][2][4 * lane] = c2;
    *(float4*)&sR[wv][3][4 * lane] = c3;
    __syncthreads();

    // ---- final reduce: wave w -> (j = w&3, h-half = w>>2) ----------------
    {
        const int jr = wv & 3;
        const int h2 = (wv >> 2) * 128 + 2 * lane;
        float sx = 0.f, sy = 0.f;
        #pragma unroll
        for (int ww = 0; ww < 8; ww++) {
            float2 tv = *(const float2*)&sR[ww][jr][h2];
            sx += tv.x; sy += tv.y;
        }
        float2 o; o.x = sx; o.y = sy;
        *(float2*)(out_c + (size_t)(jj0 + jr) * HH + h2) = o;
    }
}

extern "C" void kernel_launch(void* const* d_in, const int* in_sizes, int n_in,
                              void* d_out, int out_size, void* d_ws, size_t ws_size,
                              hipStream_t stream) {
    const float* enc = (const float*)d_in[0];
    const float* dec = (const float*)d_in[1];
    const float* Wa  = (const float*)d_in[2];
    const float* Ua  = (const float*)d_in[3];
    const float* Va  = (const float*)d_in[4];

    float* W4  = (float*)d_ws;                        // exp2-domain, interleaved (4MB)
    float* Uhe = W4 + (size_t)BB * HH * TE;           // exp2-domain, B*TD*H (2MB)

    float* out_c = (float*)d_out;                     // [B,TD,H]
    float* out_e = out_c + (size_t)BB * TD * HH;      // [B,TD,TE]

    k_pre<<<384, 256, 0, stream>>>(enc, dec, Wa, Ua, W4, Uhe);
    k_attn<<<BB * TD / 4, 512, 0, stream>>>(enc, W4, Uhe, Va, out_c, out_e);
}